// Round 8
// baseline (94.286 us; speedup 1.0000x reference)
//
#include <hip/hip_runtime.h>

#define B_  32
#define T_  4096
#define D_  256
#define D4_ 64          // D_/4 float4 columns

typedef float f32x4 __attribute__((ext_vector_type(4)));

__device__ __forceinline__ f32x4 sigmoid4(f32x4 v) {
    f32x4 r;
    r[0] = 1.0f / (1.0f + expf(-v[0]));
    r[1] = 1.0f / (1.0f + expf(-v[1]));
    r[2] = 1.0f / (1.0f + expf(-v[2]));
    r[3] = 1.0f / (1.0f + expf(-v[3]));
    return r;
}

// P1: zero-init local scan per chunk. x read ONCE via NT loads (no L3
// pollution); y_local stored to y with regular stores (dirty in L3);
// chunk aggregate written to E.
__global__ __launch_bounds__(256) void ema_local(
    const f32x4* __restrict__ x, const f32x4* __restrict__ la,
    f32x4* __restrict__ y, f32x4* __restrict__ E, int NC, int L) {
    const int wid  = threadIdx.x >> 6;
    const int lane = threadIdx.x & 63;
    const int g = blockIdx.x * 4 + wid;        // chunk-task id in [0, B_*NC)
    const int b = g / NC;
    const int c = g % NC;

    const f32x4 al = sigmoid4(la[lane]);
    const f32x4 om = 1.0f - al;

    size_t idx = ((size_t)b * T_ + (size_t)c * L) * D4_ + lane;
    f32x4 acc = 0.0f;
    int i0 = 0;
    if (c == 0) {                               // y_0 = x_0 exactly
        acc = __builtin_nontemporal_load(&x[idx]);
        y[idx] = acc;
        idx += D4_;
        i0 = 1;
    }
    #pragma unroll 8
    for (int i = i0; i < L; ++i) {
        f32x4 xv = __builtin_nontemporal_load(&x[idx]);
        acc = al * acc + om * xv;
        y[idx] = acc;                           // regular store -> L3 dirty
        idx += D4_;
    }
    E[(size_t)g * D4_ + lane] = acc;
}

// P2: fold incoming state H from predecessor aggregates (8-wide batches),
// then y_t += al^(i+1) * H  (read-modify-write, y resident in L3).
__global__ __launch_bounds__(256) void ema_fixup(
    const f32x4* __restrict__ la, const f32x4* __restrict__ E,
    f32x4* __restrict__ y, int NC, int L, int log2L) {
    const int wid  = threadIdx.x >> 6;
    const int lane = threadIdx.x & 63;
    const int g = blockIdx.x * 4 + wid;
    const int b = g / NC;
    const int c = g % NC;
    if (c == 0) return;                         // H = 0, chunk already final

    const f32x4 al = sigmoid4(la[lane]);

    f32x4 aL = al;                              // al^L via log2L squarings
    for (int k = 0; k < log2L; ++k) aL = aL * aL;
    const f32x4 aL2 = aL * aL;
    const f32x4 aL4 = aL2 * aL2;
    const f32x4 aL8 = aL4 * aL4;

    // H = sum_{j<c} aL^(c-1-j) * E[b][j]
    const f32x4* Eb = E + ((size_t)b * NC) * D4_ + lane;
    f32x4 H = 0.0f;
    int j = 0;
    for (; j + 8 <= c; j += 8) {                // 8 independent loads/round
        f32x4 e0 = Eb[(size_t)(j + 0) * D4_];
        f32x4 e1 = Eb[(size_t)(j + 1) * D4_];
        f32x4 e2 = Eb[(size_t)(j + 2) * D4_];
        f32x4 e3 = Eb[(size_t)(j + 3) * D4_];
        f32x4 e4 = Eb[(size_t)(j + 4) * D4_];
        f32x4 e5 = Eb[(size_t)(j + 5) * D4_];
        f32x4 e6 = Eb[(size_t)(j + 6) * D4_];
        f32x4 e7 = Eb[(size_t)(j + 7) * D4_];
        f32x4 t = e0;
        t = t * aL + e1;
        t = t * aL + e2;
        t = t * aL + e3;
        t = t * aL + e4;
        t = t * aL + e5;
        t = t * aL + e6;
        t = t * aL + e7;
        H = aL8 * H + t;
    }
    for (; j < c; ++j)
        H = aL * H + Eb[(size_t)j * D4_];

    // apply correction
    size_t idx = ((size_t)b * T_ + (size_t)c * L) * D4_ + lane;
    f32x4 coef = al;
    #pragma unroll 8
    for (int i = 0; i < L; ++i) {
        f32x4 v = y[idx];
        v = v + coef * H;
        y[idx] = v;
        coef = coef * al;
        idx += D4_;
    }
}

extern "C" void kernel_launch(void* const* d_in, const int* in_sizes, int n_in,
                              void* d_out, int out_size, void* d_ws, size_t ws_size,
                              hipStream_t stream) {
    const f32x4* x  = (const f32x4*)d_in[0];
    const f32x4* la = (const f32x4*)d_in[1];
    f32x4* out = (f32x4*)d_out;

    // E needs B_*NC*D_ floats in d_ws.
    int NC = 64;                                // 512 blocks, 8 waves/CU
    while (NC > 1 && (size_t)B_ * NC * D_ * sizeof(float) > ws_size) NC >>= 1;
    const int L = T_ / NC;
    int log2L = 0;
    while ((1 << log2L) < L) ++log2L;

    f32x4* E = (f32x4*)d_ws;
    const int ntasks = B_ * NC;                 // 4 chunk-tasks per block
    dim3 blk(256);
    dim3 grd(ntasks / 4);

    ema_local<<<grd, blk, 0, stream>>>(x, la, out, E, NC, L);
    ema_fixup<<<grd, blk, 0, stream>>>(la, E, out, NC, L, log2L);
}